// Round 13
// baseline (459.275 us; speedup 1.0000x reference)
//
#include <hip/hip_runtime.h>
#include <hip/hip_bf16.h>

using bf16 = __hip_bfloat16;

#define HEADS 6
#define EPSV 1e-5f
#define QS 0.17677669529663687f

typedef __bf16 bfv8 __attribute__((ext_vector_type(8)));
typedef short sv8 __attribute__((ext_vector_type(8)));
typedef float fv4 __attribute__((ext_vector_type(4)));

__device__ __forceinline__ unsigned short f2bfbits(float f) {
  union { float f; unsigned u; } x{f};
  unsigned r = x.u + 0x7fffu + ((x.u >> 16) & 1u);
  return (unsigned short)(r >> 16);
}

// swizzled index (in shorts) for row-major bf16 tile, 16B-block XOR swizzle
__device__ __forceinline__ int swz(int row, int col, int rowstride) {
  return row * rowstride + ((((col >> 3) ^ (row & 7)) << 3) | (col & 7));
}

// swizzle for 32-col (64 B/row) tiles
__device__ __forceinline__ int swz32(int row, int col) {
  return row * 32 + ((((col >> 3) ^ ((row >> 1) & 3)) << 3) | (col & 7));
}

__device__ __forceinline__ uint2 pack4b(fv4 a, float b0, float b1, float b2, float b3) {
  uint2 r;
  r.x = (unsigned)f2bfbits(a[0] + b0) | ((unsigned)f2bfbits(a[1] + b1) << 16);
  r.y = (unsigned)f2bfbits(a[2] + b2) | ((unsigned)f2bfbits(a[3] + b3) << 16);
  return r;
}

template <bool BW>
__device__ __forceinline__ bfv8 ldwf(const short* wb, const float* wf, int row,
                                     int k, int ld, float scale) {
  if constexpr (BW) {
    return *(const bfv8*)(wb + (size_t)row * ld + k);
  } else {
    const float* p = wf + (size_t)row * ld + k;
    float4 a = *(const float4*)p;
    float4 b = *(const float4*)(p + 4);
    sv8 s;
    s[0] = (short)f2bfbits(a.x * scale); s[1] = (short)f2bfbits(a.y * scale);
    s[2] = (short)f2bfbits(a.z * scale); s[3] = (short)f2bfbits(a.w * scale);
    s[4] = (short)f2bfbits(b.x * scale); s[5] = (short)f2bfbits(b.y * scale);
    s[6] = (short)f2bfbits(b.z * scale); s[7] = (short)f2bfbits(b.w * scale);
    return __builtin_bit_cast(bfv8, s);
  }
}

// ---------------- stats body ----------------
__device__ __forceinline__ void stats_body(const float* __restrict__ x, int bc,
                                           float2* __restrict__ mr, int tid) {
  const float4* p = (const float4*)(x + (size_t)bc * 16384);
  float s = 0.f, s2 = 0.f;
  for (int i = tid; i < 4096; i += 256) {
    float4 v = p[i];
    s += v.x + v.y + v.z + v.w;
    s2 = fmaf(v.x, v.x, s2);
    s2 = fmaf(v.y, v.y, s2);
    s2 = fmaf(v.z, v.z, s2);
    s2 = fmaf(v.w, v.w, s2);
  }
#pragma unroll
  for (int off = 32; off > 0; off >>= 1) {
    s += __shfl_down(s, off);
    s2 += __shfl_down(s2, off);
  }
  __shared__ float rs[4], rs2[4];
  int wid = tid >> 6;
  if ((tid & 63) == 0) { rs[wid] = s; rs2[wid] = s2; }
  __syncthreads();
  if (tid == 0) {
    float S = rs[0] + rs[1] + rs[2] + rs[3];
    float S2 = rs2[0] + rs2[1] + rs2[2] + rs2[3];
    float m = S * (1.f / 16384.f);
    float v = S2 * (1.f / 16384.f) - m * m;
    mr[bc] = make_float2(m, rsqrtf(v + EPSV));
  }
}

__global__ __launch_bounds__(256) void stats_kernel(const float* __restrict__ x,
                                                    float2* __restrict__ mr) {
  stats_body(x, blockIdx.x, mr, threadIdx.x);
}

// ---------------- merged: stats1 + FiLM + weight preconvert ----------------
__device__ __forceinline__ void pack8(float4 a, float4 b, float sc, short* dst) {
  uint4 o;
  o.x = (unsigned)f2bfbits(a.x * sc) | ((unsigned)f2bfbits(a.y * sc) << 16);
  o.y = (unsigned)f2bfbits(a.z * sc) | ((unsigned)f2bfbits(a.w * sc) << 16);
  o.z = (unsigned)f2bfbits(b.x * sc) | ((unsigned)f2bfbits(b.y * sc) << 16);
  o.w = (unsigned)f2bfbits(b.z * sc) | ((unsigned)f2bfbits(b.w * sc) << 16);
  *(uint4*)dst = o;
}

__global__ __launch_bounds__(256) void fused_pre_kernel(
    const float* __restrict__ x, float2* __restrict__ mr1,
    const float* __restrict__ cond, const float* __restrict__ fw,
    const float* __restrict__ fb, float* __restrict__ gb,
    const float* __restrict__ qkv_w, const float* __restrict__ proj_w,
    const float* __restrict__ mlp_w1, const float* __restrict__ mlp_w2,
    short* __restrict__ wbA, int nUnits) {
  int bid = blockIdx.x;
  if (bid < 1536) {
    stats_body(x, bid, mr1, threadIdx.x);
    return;
  }
  bid -= 1536;
  if (bid < 12) {
    int g = bid * 256 + threadIdx.x;
    if (g >= 8 * 384) return;
    int b = g / 384, o = g % 384;
    const float* c = cond + b * 256;
    const float* w = fw + o * 256;
    float acc = fb[o];
    for (int k = 0; k < 256; k += 4) {
      float4 cv = *(const float4*)(c + k);
      float4 wv = *(const float4*)(w + k);
      acc = fmaf(cv.x, wv.x, acc);
      acc = fmaf(cv.y, wv.y, acc);
      acc = fmaf(cv.z, wv.z, acc);
      acc = fmaf(cv.w, wv.w, acc);
    }
    gb[g] = acc;
    return;
  }
  int u = (bid - 12) * 256 + threadIdx.x;
  if (u >= nUnits) return;
  if (u < 18432) {
    int e = u * 8;
    float sc = (e < 36864) ? QS : 1.f;
    const float* src = (e < 110592) ? (qkv_w + e) : (proj_w + (e - 110592));
    pack8(*(const float4*)src, *(const float4*)(src + 4), sc, wbA + e);
  } else if (u < 36864) {
    int f = (u - 18432) * 8;
    int ob = f / 12288, s = f % 12288;
    int row = s / 192, within = s % 192;
    int col0 = (((within >> 3) ^ (row & 7)) << 3);
    const float* src = mlp_w1 + (size_t)(ob * 64 + row) * 192 + col0;
    pack8(*(const float4*)src, *(const float4*)(src + 4), 1.f, wbA + 147456 + f);
  } else {
    int f = (u - 36864) * 8;
    int chunk = f / 6144, s = f % 6144;
    int r = s / 32, within = s % 32;
    int blk = within >> 3;
    int ob = chunk >> 1, ch = chunk & 1;
    int srccol = ob * 64 + ch * 32 + ((blk ^ ((r >> 1) & 3)) << 3);
    const float* src = mlp_w2 + (size_t)r * 768 + srccol;
    pack8(*(const float4*)src, *(const float4*)(src + 4), 1.f, wbA + 294912 + f);
  }
}

// ---------------- MFMA window attention v6: V in registers, 51 KB LDS, 3 blocks/CU ----------------
template <bool BW>
__global__ __launch_bounds__(512, 3) void attn_mfma6_kernel(
    const float* __restrict__ x, const float2* __restrict__ mr1,
    const short* __restrict__ wb, const float* __restrict__ qkv_w,
    const float* __restrict__ qkv_b, const float* __restrict__ proj_w,
    const float* __restrict__ proj_b, const float* __restrict__ rel_bias,
    float* __restrict__ out) {
  __shared__ __align__(16) short s_x[64 * 192];  // normed x -> Q -> O
  __shared__ __align__(16) short s_k[64 * 192];  // K [token][d]
  __shared__ short s_relb[1350];                 // rel bias in bf16

  const short* wbq = wb;
  const short* wbp = wb + 110592;

  int tid = threadIdx.x;
  // XCD-contiguous swizzle: ww-adjacent windows (sharing 128B lines) -> same XCD
  int blk = ((blockIdx.x & 7) << 8) + (blockIdx.x >> 3);
  int b = blk >> 8;
  int wdw = blk & 255;
  int wh = wdw >> 4, ww = wdw & 15;
  int lane = tid & 63;
  int w = tid >> 6;
  int nloc = lane & 15, lg = lane >> 4;

  // per-wave V-tile ownership: units u=3w..3w+2 span heads hh_lo..hh_hi
  int hh_lo = (3 * w) >> 2;
  int hh_hi = (3 * w + 2) >> 2;
  int nvt = (hh_hi != hh_lo) ? 4 : 2;  // 16-wide d-tiles held: 2*hh_lo .. 2*hh_lo+nvt-1

  for (int i = tid; i < 1350; i += 512) s_relb[i] = (short)f2bfbits(rel_bias[i]);

  // ---- gather + instance-norm -> s_x[token][c] bf16 swizzled ----
  for (int u = tid; u < 3072; u += 512) {
    int jh = u & 1, ii = (u >> 1) & 7, c = u >> 4;
    int hg = (wh * 8 + ii + 4) & 127;
    int wc0 = (ww * 8 + jh * 4 + 4) & 127;
    float4 v = *(const float4*)&x[((size_t)(b * 192 + c) << 14) + (hg << 7) + wc0];
    float2 mrv = mr1[b * 192 + c];
    int n0 = ii * 8 + jh * 4;
    s_x[swz(n0 + 0, c, 192)] = (short)f2bfbits((v.x - mrv.x) * mrv.y);
    s_x[swz(n0 + 1, c, 192)] = (short)f2bfbits((v.y - mrv.x) * mrv.y);
    s_x[swz(n0 + 2, c, 192)] = (short)f2bfbits((v.z - mrv.x) * mrv.y);
    s_x[swz(n0 + 3, c, 192)] = (short)f2bfbits((v.w - mrv.x) * mrv.y);
  }
  __syncthreads();

  // V held in registers, bf16-packed: vpk[local d-tile][pt] (rows = 4 tokens of pt group)
  uint2 vpk[4][4];

  // ---- QKV in two token-halves ----
  for (int half = 0; half < 2; half++) {
    int ptb = half * 2;
    bfv8 xf[2][6];
#pragma unroll
    for (int pp = 0; pp < 2; pp++)
#pragma unroll
      for (int ks = 0; ks < 6; ks++)
        xf[pp][ks] = *(const bfv8*)&s_x[swz((ptb + pp) * 16 + nloc, ks * 32 + lg * 8, 192)];
    __syncthreads();  // all waves cached this half before Q overwrites it

    // Q/K tiles: 24 tiles over 8 waves (wf loads interleaved per-ks to cap live regs)
    for (int t = w; t < 24; t += 8) {
      bool isQ = (t < 12);
      float scl = (!BW && isQ) ? QS : 1.f;
      fv4 acc0 = fv4{0.f, 0.f, 0.f, 0.f};
      fv4 acc1 = fv4{0.f, 0.f, 0.f, 0.f};
      __builtin_amdgcn_s_setprio(1);
#pragma unroll
      for (int ks = 0; ks < 6; ks++) {
        bfv8 wf = ldwf<BW>(wbq, qkv_w, t * 16 + nloc, ks * 32 + lg * 8, 192, scl);
        acc0 = __builtin_amdgcn_mfma_f32_16x16x32_bf16(wf, xf[0][ks], acc0, 0, 0, 0);
        acc1 = __builtin_amdgcn_mfma_f32_16x16x32_bf16(wf, xf[1][ks], acc1, 0, 0, 0);
      }
      __builtin_amdgcn_s_setprio(0);
      int o0 = t * 16 + lg * 4;
      float4 bb = *(const float4*)&qkv_b[o0];
      float bsc = isQ ? QS : 1.f;
      uint2 pk0 = pack4b(acc0, bb.x * bsc, bb.y * bsc, bb.z * bsc, bb.w * bsc);
      uint2 pk1 = pack4b(acc1, bb.x * bsc, bb.y * bsc, bb.z * bsc, bb.w * bsc);
      if (isQ) {
        *(uint2*)&s_x[swz(ptb * 16 + nloc, o0, 192)] = pk0;
        *(uint2*)&s_x[swz((ptb + 1) * 16 + nloc, o0, 192)] = pk1;
      } else {
        *(uint2*)&s_k[swz(ptb * 16 + nloc, o0 - 192, 192)] = pk0;
        *(uint2*)&s_k[swz((ptb + 1) * 16 + nloc, o0 - 192, 192)] = pk1;
      }
    }

    // V tiles this wave will consume (duplicated across waves; MFMA is cheap here)
#pragma unroll
    for (int vt = 0; vt < 4; vt++) {
      if (vt >= nvt) break;  // wave-uniform
      int T = 2 * hh_lo + vt;
      fv4 acc0 = fv4{0.f, 0.f, 0.f, 0.f};
      fv4 acc1 = fv4{0.f, 0.f, 0.f, 0.f};
      __builtin_amdgcn_s_setprio(1);
#pragma unroll
      for (int ks = 0; ks < 6; ks++) {
        bfv8 wfv = ldwf<BW>(wbq, qkv_w, 384 + T * 16 + nloc, ks * 32 + lg * 8, 192, 1.f);
        acc0 = __builtin_amdgcn_mfma_f32_16x16x32_bf16(xf[0][ks], wfv, acc0, 0, 0, 0);
        acc1 = __builtin_amdgcn_mfma_f32_16x16x32_bf16(xf[1][ks], wfv, acc1, 0, 0, 0);
      }
      __builtin_amdgcn_s_setprio(0);
      float bv = qkv_b[384 + T * 16 + nloc];
      vpk[vt][ptb] = pack4b(acc0, bv, bv, bv, bv);
      vpk[vt][ptb + 1] = pack4b(acc1, bv, bv, bv, bv);
    }
  }
  __syncthreads();

  // ---- scores + softmax + PV : 24 units = 6 heads x 4 n-groups, 3 per wave ----
  int maskh = (wh == 15), maskw = (ww == 15);
#pragma unroll
  for (int ui = 0; ui < 3; ui++) {
    int u = w * 3 + ui;
    int hh = u >> 2, ng = u & 3;
    int n = ng * 16 + nloc;
    int i1 = n >> 3, j1 = n & 7;
    int gn = (maskh ? (i1 < 4 ? 1 : 2) : 0) * 3 + (maskw ? (j1 < 4 ? 1 : 2) : 0);

    bfv8 qf = *(const bfv8*)&s_x[swz(n, hh * 32 + lg * 8, 192)];
    fv4 sc[4];
    __builtin_amdgcn_s_setprio(1);
#pragma unroll
    for (int mt = 0; mt < 4; mt++) {
      bfv8 kf = *(const bfv8*)&s_k[swz(mt * 16 + nloc, hh * 32 + lg * 8, 192)];
      sc[mt] = __builtin_amdgcn_mfma_f32_16x16x32_bf16(kf, qf, fv4{0.f, 0.f, 0.f, 0.f}, 0, 0, 0);
    }
    __builtin_amdgcn_s_setprio(0);
    float vals[16];
#pragma unroll
    for (int mt = 0; mt < 4; mt++) {
#pragma unroll
      for (int r = 0; r < 4; r++) {
        int m = mt * 16 + lg * 4 + r;
        int i2 = m >> 3, j2 = m & 7;
        int gm = (maskh ? (i2 < 4 ? 1 : 2) : 0) * 3 + (maskw ? (j2 < 4 ? 1 : 2) : 0);
        unsigned rb = (unsigned)(unsigned short)
                          s_relb[((i1 - i2 + 7) * 15 + (j1 - j2 + 7)) * 6 + hh]
                      << 16;
        float v = sc[mt][r] + __uint_as_float(rb);
        vals[mt * 4 + r] = (gn == gm) ? v : v - 1e9f;
      }
    }
    float mx = vals[0];
#pragma unroll
    for (int q = 1; q < 16; q++) mx = fmaxf(mx, vals[q]);
    mx = fmaxf(mx, __shfl_xor(mx, 16));
    mx = fmaxf(mx, __shfl_xor(mx, 32));
    float sum = 0.f;
#pragma unroll
    for (int q = 0; q < 16; q++) {
      vals[q] = __expf(vals[q] - mx);
      sum += vals[q];
    }
    sum += __shfl_xor(sum, 16);
    sum += __shfl_xor(sum, 32);
    float inv = 1.f / sum;

    unsigned pk[4][2];
#pragma unroll
    for (int mt = 0; mt < 4; mt++) {
      pk[mt][0] = (unsigned)f2bfbits(vals[mt * 4] * inv) |
                  ((unsigned)f2bfbits(vals[mt * 4 + 1] * inv) << 16);
      pk[mt][1] = (unsigned)f2bfbits(vals[mt * 4 + 2] * inv) |
                  ((unsigned)f2bfbits(vals[mt * 4 + 3] * inv) << 16);
    }
    // redistribute P to B-fragment layout via shfl
    int sel = lg >> 1;
    int S0 = nloc + ((lg & 1) << 5);
    int S1 = S0 + 16;
    bfv8 pf[2];
#pragma unroll
    for (int ks = 0; ks < 2; ks++) {
      unsigned a0 = (unsigned)__shfl((int)pk[2 * ks][0], S0);
      unsigned b0 = (unsigned)__shfl((int)pk[2 * ks + 1][0], S0);
      unsigned a1 = (unsigned)__shfl((int)pk[2 * ks][1], S0);
      unsigned b1 = (unsigned)__shfl((int)pk[2 * ks + 1][1], S0);
      unsigned a2 = (unsigned)__shfl((int)pk[2 * ks][0], S1);
      unsigned b2 = (unsigned)__shfl((int)pk[2 * ks + 1][0], S1);
      unsigned a3 = (unsigned)__shfl((int)pk[2 * ks][1], S1);
      unsigned b3 = (unsigned)__shfl((int)pk[2 * ks + 1][1], S1);
      uint4 uu;
      uu.x = sel ? b0 : a0;
      uu.y = sel ? b1 : a1;
      uu.z = sel ? b2 : a2;
      uu.w = sel ? b3 : a3;
      pf[ks] = __builtin_bit_cast(bfv8, uu);
    }
    // build V A-frags from register vpk via the SAME shfl pattern
    bool hiv = (hh != hh_lo);
    bfv8 vf[2][2];
#pragma unroll
    for (int dt = 0; dt < 2; dt++) {
#pragma unroll
      for (int ks = 0; ks < 2; ks++) {
        uint2 cA = hiv ? vpk[2 + dt][2 * ks] : vpk[dt][2 * ks];
        uint2 cB = hiv ? vpk[2 + dt][2 * ks + 1] : vpk[dt][2 * ks + 1];
        unsigned a0 = (unsigned)__shfl((int)cA.x, S0);
        unsigned b0 = (unsigned)__shfl((int)cB.x, S0);
        unsigned a1 = (unsigned)__shfl((int)cA.y, S0);
        unsigned b1 = (unsigned)__shfl((int)cB.y, S0);
        unsigned a2 = (unsigned)__shfl((int)cA.x, S1);
        unsigned b2 = (unsigned)__shfl((int)cB.x, S1);
        unsigned a3 = (unsigned)__shfl((int)cA.y, S1);
        unsigned b3 = (unsigned)__shfl((int)cB.y, S1);
        uint4 uu;
        uu.x = sel ? b0 : a0;
        uu.y = sel ? b1 : a1;
        uu.z = sel ? b2 : a2;
        uu.w = sel ? b3 : a3;
        vf[dt][ks] = __builtin_bit_cast(bfv8, uu);
      }
    }
    // PV: O^T[d][n] = V^T . P^T ; write o into s_x
    __builtin_amdgcn_s_setprio(1);
#pragma unroll
    for (int dt = 0; dt < 2; dt++) {
      fv4 oa = fv4{0.f, 0.f, 0.f, 0.f};
#pragma unroll
      for (int ks = 0; ks < 2; ks++)
        oa = __builtin_amdgcn_mfma_f32_16x16x32_bf16(vf[dt][ks], pf[ks], oa, 0, 0, 0);
      int d0 = hh * 32 + dt * 16 + lg * 4;
      *(uint2*)&s_x[swz(n, d0, 192)] = pack4b(oa, 0.f, 0.f, 0.f, 0.f);
    }
    __builtin_amdgcn_s_setprio(0);
  }
  __syncthreads();

  // ---- proj + residual: D[c][n] transposed compute ----
  {
    int a2 = w >> 1, half = w & 1;
#pragma unroll
    for (int ci = 0; ci < 3; ci++) {
      int ct = a2 * 3 + ci;
#pragma unroll
      for (int ni = 0; ni < 2; ni++) {
        int nt = half * 2 + ni;
        fv4 acc = fv4{0.f, 0.f, 0.f, 0.f};
        __builtin_amdgcn_s_setprio(1);
#pragma unroll
        for (int ks = 0; ks < 6; ks++) {
          bfv8 wf = ldwf<BW>(wbp, proj_w, ct * 16 + nloc, ks * 32 + lg * 8, 192, 1.f);
          bfv8 of = *(const bfv8*)&s_x[swz(nt * 16 + nloc, ks * 32 + lg * 8, 192)];
          acc = __builtin_amdgcn_mfma_f32_16x16x32_bf16(wf, of, acc, 0, 0, 0);
        }
        __builtin_amdgcn_s_setprio(0);
        int n = nt * 16 + nloc;
        int ii = n >> 3, jj = n & 7;
        int hg = (wh * 8 + ii + 4) & 127;
        int wc = (ww * 8 + jj + 4) & 127;
        float4 pb4 = *(const float4*)&proj_b[ct * 16 + lg * 4];
        const float* pbp = &pb4.x;
#pragma unroll
        for (int r = 0; r < 4; r++) {
          int c = ct * 16 + lg * 4 + r;
          size_t gi = ((size_t)(b * 192 + c) << 14) + (hg << 7) + wc;
          out[gi] = x[gi] + acc[r] + pbp[r];
        }
      }
    }
  }
}

// ---------------- MFMA MLP v5: half-ob double-buffered weight staging ----------------
__global__ __launch_bounds__(512, 2) void mlp_mfma5_kernel(
    float* __restrict__ xio, const float2* __restrict__ mr2,
    const float* __restrict__ gb, const short* __restrict__ w1s,
    const short* __restrict__ w2s, const float* __restrict__ b1,
    const float* __restrict__ b2) {
  __shared__ __align__(16) short s_pool[2 * 12288];  // 48 KB: act tile, then weight dbuf
  __shared__ __align__(16) short s_h[128 * 32];      // 8 KB
  __shared__ float s_b1[768];
  __shared__ float s_mean[192], s_rstd[192], s_scale[192], s_shift[192], s_b2[192];

  int tid = threadIdx.x;
  int blk = blockIdx.x;
  int b = blk >> 7;
  int p0 = (blk & 127) << 7;
  int lane = tid & 63;
  int w = tid >> 6;

  for (int i = tid; i < 768; i += 512) s_b1[i] = b1[i];
  for (int i = tid; i < 192; i += 512) {
    float2 mrv = mr2[b * 192 + i];
    s_mean[i] = mrv.x;
    s_rstd[i] = mrv.y;
    s_scale[i] = 1.f + gb[b * 384 + i];
    s_shift[i] = gb[b * 384 + 192 + i];
    s_b2[i] = b2[i];
  }
  __syncthreads();

  for (int e = tid; e < 768; e += 512) {
    int pq = e & 31, cb = e >> 5;
    int p = pq * 4, c0 = cb * 8;
    float4 xv[8];
#pragma unroll
    for (int j = 0; j < 8; j++)
      xv[j] = *(const float4*)&xio[((size_t)(b * 192 + c0 + j) << 14) + p0 + p];
#pragma unroll
    for (int j = 0; j < 8; j++) {
      int c = c0 + j;
      float mn = s_mean[c], rs = s_rstd[c], scv = s_scale[c], sh = s_shift[c];
      xv[j].x = (xv[j].x - mn) * rs * scv + sh;
      xv[j].y = (xv[j].y - mn) * rs * scv + sh;
      xv[j].z = (xv[j].z - mn) * rs * scv + sh;
      xv[j].w = (xv[j].w - mn) * rs * scv + sh;
    }
#pragma unroll
    for (int pp = 0; pp < 4; pp++) {
      sv8 pk;
#pragma unroll
      for (int j = 0; j < 8; j++) pk[j] = (short)f2bfbits((&xv[j].x)[pp]);
      *(sv8*)&s_pool[swz(p + pp, c0, 192)] = pk;
    }
  }
  __syncthreads();

  int prow = w * 16 + (lane & 15);
  bfv8 afr[6];
#pragma unroll
  for (int ks = 0; ks < 6; ks++) {
    int c = ks * 32 + (lane >> 4) * 8;
    afr[ks] = *(const bfv8*)&s_pool[swz(prow, c, 192)];
  }
  __syncthreads();

  char* poolBytes = (char*)s_pool;
  const char* w1B = (const char*)w1s;
  const char* w2B = (const char*)w2s;

  fv4 acc2[12];
#pragma unroll
  for (int i = 0; i < 12; i++) acc2[i] = fv4{0.f, 0.f, 0.f, 0.f};

#define STAGE_HALF(hb, bufIdx)                                                        \
  {                                                                                   \
    char* dstB = poolBytes + (bufIdx)*24576;                                          \
    _Pragma("unroll") for (int j = 0; j < 3; j++) {                                   \
      int ch = w * 3 + j;                                                             \
      const char* srcB = (ch < 12) ? (w1B + (size_t)(hb)*12288 + ch * 1024)           \
                                   : (w2B + (size_t)(hb)*12288 + (ch - 12) * 1024);   \
      __builtin_amdgcn_global_load_lds(                                               \
          (const __attribute__((address_space(1))) void*)(srcB + lane * 16),          \
          (__attribute__((address_space(3))) void*)(dstB + ch * 1024), 16, 0, 0);     \
    }                                                                                 \
  }

  STAGE_HALF(0, 0);
  asm volatile("s_waitcnt vmcnt(0)" ::: "memory");
  __builtin_amdgcn_s_barrier();

  for (int i = 0; i < 24; ++i) {
    int cur = i & 1;
    if (i < 23) STAGE_HALF(i + 1, cur ^ 1);

    const short* bw1 = s_pool + cur * 12288;
    const short* bw2 = s_pool + cur * 12288 + 6144;

#pragma unroll
    for (int it = 0; it < 2; it++) {
      fv4 a1 = fv4{0.f, 0.f, 0.f, 0.f};
      int orow = it * 16 + (lane & 15);
      __builtin_amdgcn_s_setprio(1);
#pragma unroll
      for (int ks = 0; ks < 6; ks++) {
        int c = ks * 32 + (lane >> 4) * 8;
        bfv8 wf = *(const bfv8*)&bw1[swz(orow, c, 192)];
        a1 = __builtin_amdgcn_mfma_f32_16x16x32_bf16(wf, afr[ks], a1, 0, 0, 0);
      }
      __builtin_amdgcn_s_setprio(0);
      int o0 = i * 32 + it * 16 + (lane >> 4) * 4;
      unsigned short hbv[4];
#pragma unroll
      for (int r = 0; r < 4; r++) {
        float v = a1[r] + s_b1[o0 + r];
        float g = v / (1.f + __expf(-1.5957691216f * fmaf(0.044715f * v * v, v, v)));
        hbv[r] = f2bfbits(g);
      }
      uint2 pk;
      pk.x = (unsigned)hbv[0] | ((unsigned)hbv[1] << 16);
      pk.y = (unsigned)hbv[2] | ((unsigned)hbv[3] << 16);
      int ol = it * 16 + (lane >> 4) * 4;
      *(uint2*)&s_h[swz32(prow, ol)] = pk;
    }

    bfv8 hf = *(const bfv8*)&s_h[swz32(prow, (lane >> 4) * 8)];
    __builtin_amdgcn_s_setprio(1);
#pragma unroll
    for (int it2 = 0; it2 < 12; it2++) {
      int crow = it2 * 16 + (lane & 15);
      bfv8 w2f = *(const bfv8*)&bw2[swz32(crow, (lane >> 4) * 8)];
      acc2[it2] = __builtin_amdgcn_mfma_f32_16x16x32_bf16(w2f, hf, acc2[it2], 0, 0, 0);
    }
    __builtin_amdgcn_s_setprio(0);

    if (i < 23) {
      asm volatile("s_waitcnt vmcnt(0)" ::: "memory");
      __builtin_amdgcn_s_barrier();
    }
  }
#undef STAGE_HALF

  int p = p0 + w * 16 + (lane & 15);
#pragma unroll
  for (int it2 = 0; it2 < 12; it2++) {
    int c0 = it2 * 16 + (lane >> 4) * 4;
#pragma unroll
    for (int r = 0; r < 4; r++) {
      int c = c0 + r;
      size_t gi = ((size_t)(b * 192 + c) << 14) + p;
      xio[gi] += acc2[it2][r] + s_b2[c];
    }
  }
}

// ---------------- MFMA MLP fallback (fp32 weights in LDS staging) ----------------
__global__ __launch_bounds__(512, 2) void mlp_mfma_kernel(
    float* __restrict__ xio, const float2* __restrict__ mr2,
    const float* __restrict__ gb, const float* __restrict__ w1,
    const float* __restrict__ b1, const float* __restrict__ w2,
    const float* __restrict__ b2) {
  __shared__ __align__(16) short s_a[128 * 192];
  __shared__ __align__(16) short s_h[128 * 64];
  __shared__ __align__(16) short s_w1[64 * 192];
  __shared__ __align__(16) short s_w2[192 * 64];
  __shared__ float s_b1[768];
  __shared__ float s_mean[192], s_rstd[192], s_scale[192], s_shift[192], s_b2[192];

  int tid = threadIdx.x;
  int blk = blockIdx.x;
  int b = blk >> 7;
  int p0 = (blk & 127) << 7;
  int lane = tid & 63;
  int w = tid >> 6;

  for (int i = tid; i < 768; i += 512) s_b1[i] = b1[i];
  for (int i = tid; i < 192; i += 512) {
    float2 mrv = mr2[b * 192 + i];
    s_mean[i] = mrv.x;
    s_rstd[i] = mrv.y;
    s_scale[i] = 1.f + gb[b * 384 + i];
    s_shift[i] = gb[b * 384 + 192 + i];
    s_b2[i] = b2[i];
  }
  __syncthreads();

  for (int e = tid; e < 3072; e += 512) {
    int p = e & 127, cb = e >> 7;
    int c0 = cb * 8;
    sv8 pk;
#pragma unroll
    for (int j = 0; j < 8; j++) {
      int c = c0 + j;
      float xv = xio[((size_t)(b * 192 + c) << 14) + p0 + p];
      float hn = (xv - s_mean[c]) * s_rstd[c];
      pk[j] = (short)f2bfbits(hn * s_scale[c] + s_shift[c]);
    }
    *(sv8*)&s_a[swz(p, c0, 192)] = pk;
  }
  __syncthreads();

  int prow = w * 16 + (lane & 15);
  bfv8 afr[6];
#pragma unroll
  for (int ks = 0; ks < 6; ks++) {
    int c = ks * 32 + (lane >> 4) * 8;
    afr[ks] = *(const bfv8*)&s_a[swz(prow, c, 192)];
  }

  fv4 acc2[12];
#pragma unroll
  for (int i = 0; i < 12; i++) acc2[i] = fv4{0.f, 0.f, 0.f, 0.f};

  for (int ob = 0; ob < 12; ob++) {
    __syncthreads();
    for (int e = tid; e < 3072; e += 512) {
      int row = e / 48, ch4 = e % 48;
      float4 v = *(const float4*)&w1[(size_t)(ob * 64 + row) * 192 + ch4 * 4];
      uint2 pk;
      pk.x = (unsigned)f2bfbits(v.x) | ((unsigned)f2bfbits(v.y) << 16);
      pk.y = (unsigned)f2bfbits(v.z) | ((unsigned)f2bfbits(v.w) << 16);
      *(uint2*)&s_w1[swz(row, ch4 * 4, 192)] = pk;
    }
    for (int e = tid; e < 3072; e += 512) {
      int row = e >> 4, o4 = (e & 15) * 4;
      float4 v = *(const float4*)&w2[(size_t)row * 768 + ob * 64 + o4];
      uint2 pk;
      pk.x = (unsigned)f2bfbits(v.x) | ((unsigned)f2bfbits(v.y) << 16);
      pk.y = (unsigned)f2bfbits(v.z) | ((unsigned)f2bfbits(v.w) << 16);
      *(uint2*)&s_w2[swz(row, o4, 64)] = pk;
    }
    __syncthreads();

#pragma unroll
    for (int it = 0; it < 4; it++) {
      fv4 a1 = fv4{0.f, 0.f, 0.f, 0.f};
      int orow = it * 16 + (lane & 15);
#pragma unroll
      for (int ks = 0; ks < 6; ks++) {
        int c = ks * 32 + (lane >> 4) * 8;
        bfv8 wf = *(const bfv8*)&s_w1[swz(orow, c, 192)];
        a1 = __builtin_amdgcn_mfma_f32_16x16x32_bf16(wf, afr[ks], a1, 0, 0, 0);
      }
      int o0 = ob * 64 + it * 16 + (lane >> 4) * 4;
      unsigned short hb[4];
#pragma unroll
      for (int r = 0; r < 4; r++) {
        float v = a1[r] + s_b1[o0 + r];
        float g = v / (1.f + __expf(-1.5957691216f * fmaf(0.044715f * v * v, v, v)));
        hb[r] = f2bfbits(g);
      }
      uint2 pk;
      pk.x = (unsigned)hb[0] | ((unsigned)hb[1] << 16);
      pk.y = (unsigned)hb[2] | ((unsigned)hb[3] << 16);
      int ol = it * 16 + (lane >> 4) * 4;
      *(uint2*)&s_h[swz(prow, ol, 64)] = pk;
    }

#pragma unroll
    for (int ks2 = 0; ks2 < 2; ks2++) {
      int ol = ks2 * 32 + (lane >> 4) * 8;
      bfv8 hf = *(const bfv8*)&s_h[swz(prow, ol, 64)];
#pragma unroll
      for (int it2 = 0; it2 < 12; it2++) {
        int crow = it2 * 16 + (lane & 15);
        bfv8 w2f = *(const bfv8*)&s_w2[swz(crow, ol, 64)];
        acc2[it2] = __builtin_amdgcn_mfma_f32_16x16x32_bf16(w2f, hf, acc2[it2], 0, 0, 0);
      }
    }
  }

  int p = p0 + w * 16 + (lane & 15);
#pragma unroll
  for (int it2 = 0; it2 < 12; it2++) {
    int c0 = it2 * 16 + (lane >> 4) * 4;
#pragma unroll
    for (int r = 0; r < 4; r++) {
      int c = c0 + r;
      size_t gi = ((size_t)(b * 192 + c) << 14) + p;
      xio[gi] += acc2[it2][r] + s_b2[c];
    }
  }
}

extern "C" void kernel_launch(void* const* d_in, const int* in_sizes, int n_in,
                              void* d_out, int out_size, void* d_ws, size_t ws_size,
                              hipStream_t stream) {
  const float* x = (const float*)d_in[0];
  const float* cond = (const float*)d_in[1];
  const float* qkv_w = (const float*)d_in[2];
  const float* qkv_b = (const float*)d_in[3];
  const float* proj_w = (const float*)d_in[4];
  const float* proj_b = (const float*)d_in[5];
  const float* rel_bias = (const float*)d_in[6];
  const float* film_w = (const float*)d_in[7];
  const float* film_b = (const float*)d_in[8];
  const float* mlp_w1 = (const float*)d_in[9];
  const float* mlp_b1 = (const float*)d_in[10];
  const float* mlp_w2 = (const float*)d_in[11];
  const float* mlp_b2 = (const float*)d_in[12];

  float* out = (float*)d_out;
  char* wsb = (char*)d_ws;

  float2* mr1 = (float2*)wsb;
  float2* mr2 = (float2*)(wsb + 12288);
  float* gb = (float*)(wsb + 24576);
  const size_t base = 36864;
  const size_t wbB = 442368ull * 2;
  short* wbA = (short*)(wsb + base);

  bool haveA = ws_size >= base + 294912;
  bool haveM = ws_size >= base + wbB;

  int nUnits = haveM ? 55296 : (haveA ? 18432 : 0);
  fused_pre_kernel<<<1536 + 12 + (nUnits + 255) / 256, 256, 0, stream>>>(
      x, mr1, cond, film_w, film_b, gb, qkv_w, proj_w, mlp_w1, mlp_w2, wbA, nUnits);

  if (haveA)
    attn_mfma6_kernel<true><<<2048, 512, 0, stream>>>(
        x, mr1, wbA, qkv_w, qkv_b, proj_w, proj_b, rel_bias, out);
  else
    attn_mfma6_kernel<false><<<2048, 512, 0, stream>>>(
        x, mr1, wbA, qkv_w, qkv_b, proj_w, proj_b, rel_bias, out);

  stats_kernel<<<1536, 256, 0, stream>>>(out, mr2);

  if (haveM)
    mlp_mfma5_kernel<<<1024, 512, 0, stream>>>(out, mr2, gb, wbA + 147456,
                                               wbA + 294912, mlp_b1, mlp_b2);
  else
    mlp_mfma_kernel<<<1024, 512, 0, stream>>>(out, mr2, gb, mlp_w1, mlp_b1,
                                              mlp_w2, mlp_b2);
}

// Round 14
// 380.974 us; speedup vs baseline: 1.2055x; 1.2055x over previous
//
#include <hip/hip_runtime.h>
#include <hip/hip_bf16.h>

using bf16 = __hip_bfloat16;

#define HEADS 6
#define EPSV 1e-5f
#define QS 0.17677669529663687f

typedef __bf16 bfv8 __attribute__((ext_vector_type(8)));
typedef short sv8 __attribute__((ext_vector_type(8)));
typedef float fv4 __attribute__((ext_vector_type(4)));

__device__ __forceinline__ unsigned short f2bfbits(float f) {
  union { float f; unsigned u; } x{f};
  unsigned r = x.u + 0x7fffu + ((x.u >> 16) & 1u);
  return (unsigned short)(r >> 16);
}

// swizzled index (in shorts) for row-major bf16 tile, 16B-block XOR swizzle
__device__ __forceinline__ int swz(int row, int col, int rowstride) {
  return row * rowstride + ((((col >> 3) ^ (row & 7)) << 3) | (col & 7));
}

// swizzle for 32-col (64 B/row) tiles
__device__ __forceinline__ int swz32(int row, int col) {
  return row * 32 + ((((col >> 3) ^ ((row >> 1) & 3)) << 3) | (col & 7));
}

__device__ __forceinline__ uint2 pack4b(fv4 a, float b0, float b1, float b2, float b3) {
  uint2 r;
  r.x = (unsigned)f2bfbits(a[0] + b0) | ((unsigned)f2bfbits(a[1] + b1) << 16);
  r.y = (unsigned)f2bfbits(a[2] + b2) | ((unsigned)f2bfbits(a[3] + b3) << 16);
  return r;
}

template <bool BW>
__device__ __forceinline__ bfv8 ldwf(const short* wb, const float* wf, int row,
                                     int k, int ld, float scale) {
  if constexpr (BW) {
    return *(const bfv8*)(wb + (size_t)row * ld + k);
  } else {
    const float* p = wf + (size_t)row * ld + k;
    float4 a = *(const float4*)p;
    float4 b = *(const float4*)(p + 4);
    sv8 s;
    s[0] = (short)f2bfbits(a.x * scale); s[1] = (short)f2bfbits(a.y * scale);
    s[2] = (short)f2bfbits(a.z * scale); s[3] = (short)f2bfbits(a.w * scale);
    s[4] = (short)f2bfbits(b.x * scale); s[5] = (short)f2bfbits(b.y * scale);
    s[6] = (short)f2bfbits(b.z * scale); s[7] = (short)f2bfbits(b.w * scale);
    return __builtin_bit_cast(bfv8, s);
  }
}

// ---------------- stats body ----------------
__device__ __forceinline__ void stats_body(const float* __restrict__ x, int bc,
                                           float2* __restrict__ mr, int tid) {
  const float4* p = (const float4*)(x + (size_t)bc * 16384);
  float s = 0.f, s2 = 0.f;
  for (int i = tid; i < 4096; i += 256) {
    float4 v = p[i];
    s += v.x + v.y + v.z + v.w;
    s2 = fmaf(v.x, v.x, s2);
    s2 = fmaf(v.y, v.y, s2);
    s2 = fmaf(v.z, v.z, s2);
    s2 = fmaf(v.w, v.w, s2);
  }
#pragma unroll
  for (int off = 32; off > 0; off >>= 1) {
    s += __shfl_down(s, off);
    s2 += __shfl_down(s2, off);
  }
  __shared__ float rs[4], rs2[4];
  int wid = tid >> 6;
  if ((tid & 63) == 0) { rs[wid] = s; rs2[wid] = s2; }
  __syncthreads();
  if (tid == 0) {
    float S = rs[0] + rs[1] + rs[2] + rs[3];
    float S2 = rs2[0] + rs2[1] + rs2[2] + rs2[3];
    float m = S * (1.f / 16384.f);
    float v = S2 * (1.f / 16384.f) - m * m;
    mr[bc] = make_float2(m, rsqrtf(v + EPSV));
  }
}

__global__ __launch_bounds__(256) void stats_kernel(const float* __restrict__ x,
                                                    float2* __restrict__ mr) {
  stats_body(x, blockIdx.x, mr, threadIdx.x);
}

// ---------------- merged: stats1 + FiLM + weight preconvert ----------------
__device__ __forceinline__ void pack8(float4 a, float4 b, float sc, short* dst) {
  uint4 o;
  o.x = (unsigned)f2bfbits(a.x * sc) | ((unsigned)f2bfbits(a.y * sc) << 16);
  o.y = (unsigned)f2bfbits(a.z * sc) | ((unsigned)f2bfbits(a.w * sc) << 16);
  o.z = (unsigned)f2bfbits(b.x * sc) | ((unsigned)f2bfbits(b.y * sc) << 16);
  o.w = (unsigned)f2bfbits(b.z * sc) | ((unsigned)f2bfbits(b.w * sc) << 16);
  *(uint4*)dst = o;
}

__global__ __launch_bounds__(256) void fused_pre_kernel(
    const float* __restrict__ x, float2* __restrict__ mr1,
    const float* __restrict__ cond, const float* __restrict__ fw,
    const float* __restrict__ fb, float* __restrict__ gb,
    const float* __restrict__ qkv_w, const float* __restrict__ proj_w,
    const float* __restrict__ mlp_w1, const float* __restrict__ mlp_w2,
    short* __restrict__ wbA, int nUnits) {
  int bid = blockIdx.x;
  if (bid < 1536) {
    stats_body(x, bid, mr1, threadIdx.x);
    return;
  }
  bid -= 1536;
  if (bid < 12) {
    int g = bid * 256 + threadIdx.x;
    if (g >= 8 * 384) return;
    int b = g / 384, o = g % 384;
    const float* c = cond + b * 256;
    const float* w = fw + o * 256;
    float acc = fb[o];
    for (int k = 0; k < 256; k += 4) {
      float4 cv = *(const float4*)(c + k);
      float4 wv = *(const float4*)(w + k);
      acc = fmaf(cv.x, wv.x, acc);
      acc = fmaf(cv.y, wv.y, acc);
      acc = fmaf(cv.z, wv.z, acc);
      acc = fmaf(cv.w, wv.w, acc);
    }
    gb[g] = acc;
    return;
  }
  int u = (bid - 12) * 256 + threadIdx.x;
  if (u >= nUnits) return;
  if (u < 18432) {
    int e = u * 8;
    float sc = (e < 36864) ? QS : 1.f;
    const float* src = (e < 110592) ? (qkv_w + e) : (proj_w + (e - 110592));
    pack8(*(const float4*)src, *(const float4*)(src + 4), sc, wbA + e);
  } else if (u < 36864) {
    int f = (u - 18432) * 8;
    int ob = f / 12288, s = f % 12288;
    int row = s / 192, within = s % 192;
    int col0 = (((within >> 3) ^ (row & 7)) << 3);
    const float* src = mlp_w1 + (size_t)(ob * 64 + row) * 192 + col0;
    pack8(*(const float4*)src, *(const float4*)(src + 4), 1.f, wbA + 147456 + f);
  } else {
    int f = (u - 36864) * 8;
    int chunk = f / 6144, s = f % 6144;
    int r = s / 32, within = s % 32;
    int blk = within >> 3;
    int ob = chunk >> 1, ch = chunk & 1;
    int srccol = ob * 64 + ch * 32 + ((blk ^ ((r >> 1) & 3)) << 3);
    const float* src = mlp_w2 + (size_t)r * 768 + srccol;
    pack8(*(const float4*)src, *(const float4*)(src + 4), 1.f, wbA + 294912 + f);
  }
}

// ---------------- MFMA window attention v7: round-12 structure + bf16 rel bias ----------------
template <bool BW>
__global__ __launch_bounds__(512, 4) void attn_mfma7_kernel(
    const float* __restrict__ x, const float2* __restrict__ mr1,
    const short* __restrict__ wb, const float* __restrict__ qkv_w,
    const float* __restrict__ qkv_b, const float* __restrict__ proj_w,
    const float* __restrict__ proj_b, const float* __restrict__ rel_bias,
    float* __restrict__ out) {
  __shared__ __align__(16) short s_x[64 * 192];  // normed x -> Q -> O
  __shared__ __align__(16) short s_k[64 * 192];  // K [token][d]
  __shared__ __align__(16) short s_v[192 * 64];  // V^T [d][token]
  __shared__ short s_relb[1350];                 // rel bias, bf16 (validated r13)

  const short* wbq = wb;
  const short* wbp = wb + 110592;

  int tid = threadIdx.x;
  // XCD-contiguous swizzle: ww-adjacent windows (sharing 128B lines) -> same XCD
  int blk = ((blockIdx.x & 7) << 8) + (blockIdx.x >> 3);
  int b = blk >> 8;
  int wdw = blk & 255;
  int wh = wdw >> 4, ww = wdw & 15;
  int lane = tid & 63;
  int w = tid >> 6;
  int nloc = lane & 15, lg = lane >> 4;

  for (int i = tid; i < 1350; i += 512) s_relb[i] = (short)f2bfbits(rel_bias[i]);

  // ---- gather + instance-norm -> s_x[token][c] bf16 swizzled ----
  for (int u = tid; u < 3072; u += 512) {
    int jh = u & 1, ii = (u >> 1) & 7, c = u >> 4;
    int hg = (wh * 8 + ii + 4) & 127;
    int wc0 = (ww * 8 + jh * 4 + 4) & 127;
    float4 v = *(const float4*)&x[((size_t)(b * 192 + c) << 14) + (hg << 7) + wc0];
    float2 mrv = mr1[b * 192 + c];
    int n0 = ii * 8 + jh * 4;
    s_x[swz(n0 + 0, c, 192)] = (short)f2bfbits((v.x - mrv.x) * mrv.y);
    s_x[swz(n0 + 1, c, 192)] = (short)f2bfbits((v.y - mrv.x) * mrv.y);
    s_x[swz(n0 + 2, c, 192)] = (short)f2bfbits((v.z - mrv.x) * mrv.y);
    s_x[swz(n0 + 3, c, 192)] = (short)f2bfbits((v.w - mrv.x) * mrv.y);
  }
  __syncthreads();

  // ---- QKV in two token-halves (keeps VGPR <= 64) ----
  for (int half = 0; half < 2; half++) {
    int ptb = half * 2;
    bfv8 xf[2][6];
#pragma unroll
    for (int pp = 0; pp < 2; pp++)
#pragma unroll
      for (int ks = 0; ks < 6; ks++)
        xf[pp][ks] = *(const bfv8*)&s_x[swz((ptb + pp) * 16 + nloc, ks * 32 + lg * 8, 192)];
    __syncthreads();  // all waves cached this half before Q overwrites it

    for (int t = w; t < 36; t += 8) {
      bool isQK = (t < 24);
      int baserow = isQK ? t * 16 : 384 + (t - 24) * 16;
      float scl = (!BW && t < 12) ? QS : 1.f;
      bfv8 wf[6];
#pragma unroll
      for (int ks = 0; ks < 6; ks++)
        wf[ks] = ldwf<BW>(wbq, qkv_w, baserow + nloc, ks * 32 + lg * 8, 192, scl);
      __builtin_amdgcn_s_setprio(1);
#pragma unroll
      for (int pp = 0; pp < 2; pp++) {
        int pt = ptb + pp;
        fv4 acc = fv4{0.f, 0.f, 0.f, 0.f};
        if (isQK) {
#pragma unroll
          for (int ks = 0; ks < 6; ks++)
            acc = __builtin_amdgcn_mfma_f32_16x16x32_bf16(wf[ks], xf[pp][ks], acc, 0, 0, 0);
          int o0 = t * 16 + lg * 4;
          float4 bb = *(const float4*)&qkv_b[o0];
          float bsc = (t < 12) ? QS : 1.f;
          uint2 pkk = pack4b(acc, bb.x * bsc, bb.y * bsc, bb.z * bsc, bb.w * bsc);
          if (t < 12)
            *(uint2*)&s_x[swz(pt * 16 + nloc, o0, 192)] = pkk;
          else
            *(uint2*)&s_k[swz(pt * 16 + nloc, o0 - 192, 192)] = pkk;
        } else {
#pragma unroll
          for (int ks = 0; ks < 6; ks++)
            acc = __builtin_amdgcn_mfma_f32_16x16x32_bf16(xf[pp][ks], wf[ks], acc, 0, 0, 0);
          int d = (t - 24) * 16 + nloc;
          float bv = qkv_b[384 + d];
          *(uint2*)&s_v[swz(d, pt * 16 + lg * 4, 64)] = pack4b(acc, bv, bv, bv, bv);
        }
      }
      __builtin_amdgcn_s_setprio(0);
    }
  }
  __syncthreads();

  // ---- scores + softmax + PV : 24 units = 6 heads x 4 n-groups, 3 per wave ----
  int maskh = (wh == 15), maskw = (ww == 15);
#pragma unroll
  for (int ui = 0; ui < 3; ui++) {
    int u = w * 3 + ui;
    int hh = u >> 2, ng = u & 3;
    int n = ng * 16 + nloc;
    int i1 = n >> 3, j1 = n & 7;
    int gn = (maskh ? (i1 < 4 ? 1 : 2) : 0) * 3 + (maskw ? (j1 < 4 ? 1 : 2) : 0);

    bfv8 qf = *(const bfv8*)&s_x[swz(n, hh * 32 + lg * 8, 192)];
    fv4 sc[4];
    __builtin_amdgcn_s_setprio(1);
#pragma unroll
    for (int mt = 0; mt < 4; mt++) {
      bfv8 kf = *(const bfv8*)&s_k[swz(mt * 16 + nloc, hh * 32 + lg * 8, 192)];
      sc[mt] = __builtin_amdgcn_mfma_f32_16x16x32_bf16(kf, qf, fv4{0.f, 0.f, 0.f, 0.f}, 0, 0, 0);
    }
    __builtin_amdgcn_s_setprio(0);
    float vals[16];
#pragma unroll
    for (int mt = 0; mt < 4; mt++) {
#pragma unroll
      for (int r = 0; r < 4; r++) {
        int m = mt * 16 + lg * 4 + r;
        int i2 = m >> 3, j2 = m & 7;
        int gm = (maskh ? (i2 < 4 ? 1 : 2) : 0) * 3 + (maskw ? (j2 < 4 ? 1 : 2) : 0);
        unsigned rb = (unsigned)(unsigned short)
                          s_relb[((i1 - i2 + 7) * 15 + (j1 - j2 + 7)) * 6 + hh]
                      << 16;
        float v = sc[mt][r] + __uint_as_float(rb);
        vals[mt * 4 + r] = (gn == gm) ? v : v - 1e9f;
      }
    }
    float mx = vals[0];
#pragma unroll
    for (int q = 1; q < 16; q++) mx = fmaxf(mx, vals[q]);
    mx = fmaxf(mx, __shfl_xor(mx, 16));
    mx = fmaxf(mx, __shfl_xor(mx, 32));
    float sum = 0.f;
#pragma unroll
    for (int q = 0; q < 16; q++) {
      vals[q] = __expf(vals[q] - mx);
      sum += vals[q];
    }
    sum += __shfl_xor(sum, 16);
    sum += __shfl_xor(sum, 32);
    float inv = 1.f / sum;

    unsigned pk[4][2];
#pragma unroll
    for (int mt = 0; mt < 4; mt++) {
      pk[mt][0] = (unsigned)f2bfbits(vals[mt * 4] * inv) |
                  ((unsigned)f2bfbits(vals[mt * 4 + 1] * inv) << 16);
      pk[mt][1] = (unsigned)f2bfbits(vals[mt * 4 + 2] * inv) |
                  ((unsigned)f2bfbits(vals[mt * 4 + 3] * inv) << 16);
    }
    // redistribute P to B-fragment layout via shfl
    int sel = lg >> 1;
    int S0 = nloc + ((lg & 1) << 5);
    int S1 = S0 + 16;
    bfv8 pf[2];
#pragma unroll
    for (int ks = 0; ks < 2; ks++) {
      unsigned a0 = (unsigned)__shfl((int)pk[2 * ks][0], S0);
      unsigned b0 = (unsigned)__shfl((int)pk[2 * ks + 1][0], S0);
      unsigned a1 = (unsigned)__shfl((int)pk[2 * ks][1], S0);
      unsigned b1 = (unsigned)__shfl((int)pk[2 * ks + 1][1], S0);
      unsigned a2 = (unsigned)__shfl((int)pk[2 * ks][0], S1);
      unsigned b2 = (unsigned)__shfl((int)pk[2 * ks + 1][0], S1);
      unsigned a3 = (unsigned)__shfl((int)pk[2 * ks][1], S1);
      unsigned b3 = (unsigned)__shfl((int)pk[2 * ks + 1][1], S1);
      uint4 uu;
      uu.x = sel ? b0 : a0;
      uu.y = sel ? b1 : a1;
      uu.z = sel ? b2 : a2;
      uu.w = sel ? b3 : a3;
      pf[ks] = __builtin_bit_cast(bfv8, uu);
    }
    // PV: O^T[d][n] = V^T . P^T ; write o into s_x
    __builtin_amdgcn_s_setprio(1);
#pragma unroll
    for (int dt = 0; dt < 2; dt++) {
      fv4 oa = fv4{0.f, 0.f, 0.f, 0.f};
#pragma unroll
      for (int ks = 0; ks < 2; ks++) {
        bfv8 vf = *(const bfv8*)&s_v[swz(hh * 32 + dt * 16 + nloc, ks * 32 + lg * 8, 64)];
        oa = __builtin_amdgcn_mfma_f32_16x16x32_bf16(vf, pf[ks], oa, 0, 0, 0);
      }
      int d0 = hh * 32 + dt * 16 + lg * 4;
      *(uint2*)&s_x[swz(n, d0, 192)] = pack4b(oa, 0.f, 0.f, 0.f, 0.f);
    }
    __builtin_amdgcn_s_setprio(0);
  }
  __syncthreads();

  // ---- proj + residual: D[c][n] transposed compute ----
  {
    int a2 = w >> 1, half = w & 1;
#pragma unroll
    for (int ci = 0; ci < 3; ci++) {
      int ct = a2 * 3 + ci;
      bfv8 wf[6];
#pragma unroll
      for (int ks = 0; ks < 6; ks++)
        wf[ks] = ldwf<BW>(wbp, proj_w, ct * 16 + nloc, ks * 32 + lg * 8, 192, 1.f);
#pragma unroll
      for (int ni = 0; ni < 2; ni++) {
        int nt = half * 2 + ni;
        fv4 acc = fv4{0.f, 0.f, 0.f, 0.f};
        __builtin_amdgcn_s_setprio(1);
#pragma unroll
        for (int ks = 0; ks < 6; ks++) {
          bfv8 of = *(const bfv8*)&s_x[swz(nt * 16 + nloc, ks * 32 + lg * 8, 192)];
          acc = __builtin_amdgcn_mfma_f32_16x16x32_bf16(wf[ks], of, acc, 0, 0, 0);
        }
        __builtin_amdgcn_s_setprio(0);
        int n = nt * 16 + nloc;
        int ii = n >> 3, jj = n & 7;
        int hg = (wh * 8 + ii + 4) & 127;
        int wc = (ww * 8 + jj + 4) & 127;
        float4 pb4 = *(const float4*)&proj_b[ct * 16 + lg * 4];
        const float* pbp = &pb4.x;
#pragma unroll
        for (int r = 0; r < 4; r++) {
          int c = ct * 16 + lg * 4 + r;
          size_t gi = ((size_t)(b * 192 + c) << 14) + (hg << 7) + wc;
          out[gi] = x[gi] + acc[r] + pbp[r];
        }
      }
    }
  }
}

// ---------------- MFMA MLP v5: half-ob double-buffered weight staging ----------------
__global__ __launch_bounds__(512, 2) void mlp_mfma5_kernel(
    float* __restrict__ xio, const float2* __restrict__ mr2,
    const float* __restrict__ gb, const short* __restrict__ w1s,
    const short* __restrict__ w2s, const float* __restrict__ b1,
    const float* __restrict__ b2) {
  __shared__ __align__(16) short s_pool[2 * 12288];  // 48 KB: act tile, then weight dbuf
  __shared__ __align__(16) short s_h[128 * 32];      // 8 KB
  __shared__ float s_b1[768];
  __shared__ float s_mean[192], s_rstd[192], s_scale[192], s_shift[192], s_b2[192];

  int tid = threadIdx.x;
  int blk = blockIdx.x;
  int b = blk >> 7;
  int p0 = (blk & 127) << 7;
  int lane = tid & 63;
  int w = tid >> 6;

  for (int i = tid; i < 768; i += 512) s_b1[i] = b1[i];
  for (int i = tid; i < 192; i += 512) {
    float2 mrv = mr2[b * 192 + i];
    s_mean[i] = mrv.x;
    s_rstd[i] = mrv.y;
    s_scale[i] = 1.f + gb[b * 384 + i];
    s_shift[i] = gb[b * 384 + 192 + i];
    s_b2[i] = b2[i];
  }
  __syncthreads();

  for (int e = tid; e < 768; e += 512) {
    int pq = e & 31, cb = e >> 5;
    int p = pq * 4, c0 = cb * 8;
    float4 xv[8];
#pragma unroll
    for (int j = 0; j < 8; j++)
      xv[j] = *(const float4*)&xio[((size_t)(b * 192 + c0 + j) << 14) + p0 + p];
#pragma unroll
    for (int j = 0; j < 8; j++) {
      int c = c0 + j;
      float mn = s_mean[c], rs = s_rstd[c], scv = s_scale[c], sh = s_shift[c];
      xv[j].x = (xv[j].x - mn) * rs * scv + sh;
      xv[j].y = (xv[j].y - mn) * rs * scv + sh;
      xv[j].z = (xv[j].z - mn) * rs * scv + sh;
      xv[j].w = (xv[j].w - mn) * rs * scv + sh;
    }
#pragma unroll
    for (int pp = 0; pp < 4; pp++) {
      sv8 pk;
#pragma unroll
      for (int j = 0; j < 8; j++) pk[j] = (short)f2bfbits((&xv[j].x)[pp]);
      *(sv8*)&s_pool[swz(p + pp, c0, 192)] = pk;
    }
  }
  __syncthreads();

  int prow = w * 16 + (lane & 15);
  bfv8 afr[6];
#pragma unroll
  for (int ks = 0; ks < 6; ks++) {
    int c = ks * 32 + (lane >> 4) * 8;
    afr[ks] = *(const bfv8*)&s_pool[swz(prow, c, 192)];
  }
  __syncthreads();

  char* poolBytes = (char*)s_pool;
  const char* w1B = (const char*)w1s;
  const char* w2B = (const char*)w2s;

  fv4 acc2[12];
#pragma unroll
  for (int i = 0; i < 12; i++) acc2[i] = fv4{0.f, 0.f, 0.f, 0.f};

#define STAGE_HALF(hb, bufIdx)                                                        \
  {                                                                                   \
    char* dstB = poolBytes + (bufIdx)*24576;                                          \
    _Pragma("unroll") for (int j = 0; j < 3; j++) {                                   \
      int ch = w * 3 + j;                                                             \
      const char* srcB = (ch < 12) ? (w1B + (size_t)(hb)*12288 + ch * 1024)           \
                                   : (w2B + (size_t)(hb)*12288 + (ch - 12) * 1024);   \
      __builtin_amdgcn_global_load_lds(                                               \
          (const __attribute__((address_space(1))) void*)(srcB + lane * 16),          \
          (__attribute__((address_space(3))) void*)(dstB + ch * 1024), 16, 0, 0);     \
    }                                                                                 \
  }

  STAGE_HALF(0, 0);
  asm volatile("s_waitcnt vmcnt(0)" ::: "memory");
  __builtin_amdgcn_s_barrier();

  for (int i = 0; i < 24; ++i) {
    int cur = i & 1;
    if (i < 23) STAGE_HALF(i + 1, cur ^ 1);

    const short* bw1 = s_pool + cur * 12288;
    const short* bw2 = s_pool + cur * 12288 + 6144;

#pragma unroll
    for (int it = 0; it < 2; it++) {
      fv4 a1 = fv4{0.f, 0.f, 0.f, 0.f};
      int orow = it * 16 + (lane & 15);
      __builtin_amdgcn_s_setprio(1);
#pragma unroll
      for (int ks = 0; ks < 6; ks++) {
        int c = ks * 32 + (lane >> 4) * 8;
        bfv8 wf = *(const bfv8*)&bw1[swz(orow, c, 192)];
        a1 = __builtin_amdgcn_mfma_f32_16x16x32_bf16(wf, afr[ks], a1, 0, 0, 0);
      }
      __builtin_amdgcn_s_setprio(0);
      int o0 = i * 32 + it * 16 + (lane >> 4) * 4;
      unsigned short hbv[4];
#pragma unroll
      for (int r = 0; r < 4; r++) {
        float v = a1[r] + s_b1[o0 + r];
        float g = v / (1.f + __expf(-1.5957691216f * fmaf(0.044715f * v * v, v, v)));
        hbv[r] = f2bfbits(g);
      }
      uint2 pk;
      pk.x = (unsigned)hbv[0] | ((unsigned)hbv[1] << 16);
      pk.y = (unsigned)hbv[2] | ((unsigned)hbv[3] << 16);
      int ol = it * 16 + (lane >> 4) * 4;
      *(uint2*)&s_h[swz32(prow, ol)] = pk;
    }

    bfv8 hf = *(const bfv8*)&s_h[swz32(prow, (lane >> 4) * 8)];
    __builtin_amdgcn_s_setprio(1);
#pragma unroll
    for (int it2 = 0; it2 < 12; it2++) {
      int crow = it2 * 16 + (lane & 15);
      bfv8 w2f = *(const bfv8*)&bw2[swz32(crow, (lane >> 4) * 8)];
      acc2[it2] = __builtin_amdgcn_mfma_f32_16x16x32_bf16(w2f, hf, acc2[it2], 0, 0, 0);
    }
    __builtin_amdgcn_s_setprio(0);

    if (i < 23) {
      asm volatile("s_waitcnt vmcnt(0)" ::: "memory");
      __builtin_amdgcn_s_barrier();
    }
  }
#undef STAGE_HALF

  int p = p0 + w * 16 + (lane & 15);
#pragma unroll
  for (int it2 = 0; it2 < 12; it2++) {
    int c0 = it2 * 16 + (lane >> 4) * 4;
#pragma unroll
    for (int r = 0; r < 4; r++) {
      int c = c0 + r;
      size_t gi = ((size_t)(b * 192 + c) << 14) + p;
      xio[gi] += acc2[it2][r] + s_b2[c];
    }
  }
}

// ---------------- MFMA MLP fallback (fp32 weights in LDS staging) ----------------
__global__ __launch_bounds__(512, 2) void mlp_mfma_kernel(
    float* __restrict__ xio, const float2* __restrict__ mr2,
    const float* __restrict__ gb, const float* __restrict__ w1,
    const float* __restrict__ b1, const float* __restrict__ w2,
    const float* __restrict__ b2) {
  __shared__ __align__(16) short s_a[128 * 192];
  __shared__ __align__(16) short s_h[128 * 64];
  __shared__ __align__(16) short s_w1[64 * 192];
  __shared__ __align__(16) short s_w2[192 * 64];
  __shared__ float s_b1[768];
  __shared__ float s_mean[192], s_rstd[192], s_scale[192], s_shift[192], s_b2[192];

  int tid = threadIdx.x;
  int blk = blockIdx.x;
  int b = blk >> 7;
  int p0 = (blk & 127) << 7;
  int lane = tid & 63;
  int w = tid >> 6;

  for (int i = tid; i < 768; i += 512) s_b1[i] = b1[i];
  for (int i = tid; i < 192; i += 512) {
    float2 mrv = mr2[b * 192 + i];
    s_mean[i] = mrv.x;
    s_rstd[i] = mrv.y;
    s_scale[i] = 1.f + gb[b * 384 + i];
    s_shift[i] = gb[b * 384 + 192 + i];
    s_b2[i] = b2[i];
  }
  __syncthreads();

  for (int e = tid; e < 3072; e += 512) {
    int p = e & 127, cb = e >> 7;
    int c0 = cb * 8;
    sv8 pk;
#pragma unroll
    for (int j = 0; j < 8; j++) {
      int c = c0 + j;
      float xv = xio[((size_t)(b * 192 + c) << 14) + p0 + p];
      float hn = (xv - s_mean[c]) * s_rstd[c];
      pk[j] = (short)f2bfbits(hn * s_scale[c] + s_shift[c]);
    }
    *(sv8*)&s_a[swz(p, c0, 192)] = pk;
  }
  __syncthreads();

  int prow = w * 16 + (lane & 15);
  bfv8 afr[6];
#pragma unroll
  for (int ks = 0; ks < 6; ks++) {
    int c = ks * 32 + (lane >> 4) * 8;
    afr[ks] = *(const bfv8*)&s_a[swz(prow, c, 192)];
  }

  fv4 acc2[12];
#pragma unroll
  for (int i = 0; i < 12; i++) acc2[i] = fv4{0.f, 0.f, 0.f, 0.f};

  for (int ob = 0; ob < 12; ob++) {
    __syncthreads();
    for (int e = tid; e < 3072; e += 512) {
      int row = e / 48, ch4 = e % 48;
      float4 v = *(const float4*)&w1[(size_t)(ob * 64 + row) * 192 + ch4 * 4];
      uint2 pk;
      pk.x = (unsigned)f2bfbits(v.x) | ((unsigned)f2bfbits(v.y) << 16);
      pk.y = (unsigned)f2bfbits(v.z) | ((unsigned)f2bfbits(v.w) << 16);
      *(uint2*)&s_w1[swz(row, ch4 * 4, 192)] = pk;
    }
    for (int e = tid; e < 3072; e += 512) {
      int row = e >> 4, o4 = (e & 15) * 4;
      float4 v = *(const float4*)&w2[(size_t)row * 768 + ob * 64 + o4];
      uint2 pk;
      pk.x = (unsigned)f2bfbits(v.x) | ((unsigned)f2bfbits(v.y) << 16);
      pk.y = (unsigned)f2bfbits(v.z) | ((unsigned)f2bfbits(v.w) << 16);
      *(uint2*)&s_w2[swz(row, o4, 64)] = pk;
    }
    __syncthreads();

#pragma unroll
    for (int it = 0; it < 4; it++) {
      fv4 a1 = fv4{0.f, 0.f, 0.f, 0.f};
      int orow = it * 16 + (lane & 15);
#pragma unroll
      for (int ks = 0; ks < 6; ks++) {
        int c = ks * 32 + (lane >> 4) * 8;
        bfv8 wf = *(const bfv8*)&s_w1[swz(orow, c, 192)];
        a1 = __builtin_amdgcn_mfma_f32_16x16x32_bf16(wf, afr[ks], a1, 0, 0, 0);
      }
      int o0 = ob * 64 + it * 16 + (lane >> 4) * 4;
      unsigned short hb[4];
#pragma unroll
      for (int r = 0; r < 4; r++) {
        float v = a1[r] + s_b1[o0 + r];
        float g = v / (1.f + __expf(-1.5957691216f * fmaf(0.044715f * v * v, v, v)));
        hb[r] = f2bfbits(g);
      }
      uint2 pk;
      pk.x = (unsigned)hb[0] | ((unsigned)hb[1] << 16);
      pk.y = (unsigned)hb[2] | ((unsigned)hb[3] << 16);
      int ol = it * 16 + (lane >> 4) * 4;
      *(uint2*)&s_h[swz(prow, ol, 64)] = pk;
    }

#pragma unroll
    for (int ks2 = 0; ks2 < 2; ks2++) {
      int ol = ks2 * 32 + (lane >> 4) * 8;
      bfv8 hf = *(const bfv8*)&s_h[swz(prow, ol, 64)];
#pragma unroll
      for (int it2 = 0; it2 < 12; it2++) {
        int crow = it2 * 16 + (lane & 15);
        bfv8 w2f = *(const bfv8*)&s_w2[swz(crow, ol, 64)];
        acc2[it2] = __builtin_amdgcn_mfma_f32_16x16x32_bf16(w2f, hf, acc2[it2], 0, 0, 0);
      }
    }
  }

  int p = p0 + w * 16 + (lane & 15);
#pragma unroll
  for (int it2 = 0; it2 < 12; it2++) {
    int c0 = it2 * 16 + (lane >> 4) * 4;
#pragma unroll
    for (int r = 0; r < 4; r++) {
      int c = c0 + r;
      size_t gi = ((size_t)(b * 192 + c) << 14) + p;
      xio[gi] += acc2[it2][r] + s_b2[c];
    }
  }
}

extern "C" void kernel_launch(void* const* d_in, const int* in_sizes, int n_in,
                              void* d_out, int out_size, void* d_ws, size_t ws_size,
                              hipStream_t stream) {
  const float* x = (const float*)d_in[0];
  const float* cond = (const float*)d_in[1];
  const float* qkv_w = (const float*)d_in[2];
  const float* qkv_b = (const float*)d_in[3];
  const float* proj_w = (const float*)d_in[4];
  const float* proj_b = (const float*)d_in[5];
  const float* rel_bias = (const float*)d_in[6];
  const float* film_w = (const float*)d_in[7];
  const float* film_b = (const float*)d_in[8];
  const float* mlp_w1 = (const float*)d_in[9];
  const float* mlp_b1 = (const float*)d_in[10];
  const float* mlp_w2 = (const float*)d_in[11];
  const float* mlp_b2 = (const float*)d_in[12];

  float* out = (float*)d_out;
  char* wsb = (char*)d_ws;

  float2* mr1 = (float2*)wsb;
  float2* mr2 = (float2*)(wsb + 12288);
  float* gb = (float*)(wsb + 24576);
  const size_t base = 36864;
  const size_t wbB = 442368ull * 2;
  short* wbA = (short*)(wsb + base);

  bool haveA = ws_size >= base + 294912;
  bool haveM = ws_size >= base + wbB;

  int nUnits = haveM ? 55296 : (haveA ? 18432 : 0);
  fused_pre_kernel<<<1536 + 12 + (nUnits + 255) / 256, 256, 0, stream>>>(
      x, mr1, cond, film_w, film_b, gb, qkv_w, proj_w, mlp_w1, mlp_w2, wbA, nUnits);

  if (haveA)
    attn_mfma7_kernel<true><<<2048, 512, 0, stream>>>(
        x, mr1, wbA, qkv_w, qkv_b, proj_w, proj_b, rel_bias, out);
  else
    attn_mfma7_kernel<false><<<2048, 512, 0, stream>>>(
        x, mr1, wbA, qkv_w, qkv_b, proj_w, proj_b, rel_bias, out);

  stats_kernel<<<1536, 256, 0, stream>>>(out, mr2);

  if (haveM)
    mlp_mfma5_kernel<<<1024, 512, 0, stream>>>(out, mr2, gb, wbA + 147456,
                                               wbA + 294912, mlp_b1, mlp_b2);
  else
    mlp_mfma_kernel<<<1024, 512, 0, stream>>>(out, mr2, gb, mlp_w1, mlp_b1,
                                              mlp_w2, mlp_b2);
}